// Round 1
// baseline (400.019 us; speedup 1.0000x reference)
//
#include <hip/hip_runtime.h>
#include <cstdint>
#include <cstddef>

typedef unsigned short u16;
typedef unsigned int u32;
typedef __attribute__((ext_vector_type(8))) short short8;
typedef __attribute__((ext_vector_type(4))) float floatx4;
typedef __attribute__((ext_vector_type(4))) u16 u16x4;

#define DEV static __device__ __forceinline__

DEV u16 f2b(float f){ u32 u = __float_as_uint(f); u32 r = u + 0x7fffu + ((u>>16)&1u); return (u16)(r>>16); }
DEV float b2f(u16 u){ return __uint_as_float(((u32)u)<<16); }
DEV float softplusf(float z){ return fmaxf(z,0.f) + log1pf(__expf(-fabsf(z))); }
DEV float fast_tanhf(float u){ float e = __expf(2.f*u); return 1.f - 2.f/(e+1.f); }
DEV float geluf(float x){ float u = 0.7978845608028654f*(x + 0.044715f*x*x*x); return 0.5f*x*(1.f+fast_tanhf(u)); }

DEV void async_copy16(const void* gp, void* lp){
  __builtin_amdgcn_global_load_lds((const __attribute__((address_space(1))) u32*)gp,
                                   (__attribute__((address_space(3))) u32*)lp, 16, 0, 0);
}

// ---------------- cast kernels ----------------
__global__ void cast_kernel(const float* __restrict__ src, u16* __restrict__ dst, int n){
  int i = blockIdx.x*256 + threadIdx.x;
  if (i < n) dst[i] = f2b(src[i]);
}

// W_dbc is (96,1024); pad to (128,1024) with zeros so the 128-wide N tile is valid.
__global__ void cast_dbc_pad(const float* __restrict__ src, u16* __restrict__ dst){
  int i = blockIdx.x*256 + threadIdx.x;          // 131072 = 128*1024
  int r = i >> 10;
  dst[i] = (r < 96) ? f2b(src[i]) : (u16)0;
}

// dbc bf16 cols [64,96) -> f32 B/C buffer [token][32] for scalar loads in the scan
__global__ void bc_conv(const u16* __restrict__ dbc, float* __restrict__ BCf){
  int i = blockIdx.x*256 + threadIdx.x;          // 131072 = 4096*32
  int t = i >> 5, j = i & 31;
  BCf[i] = b2f(dbc[t*128 + 64 + j]);
}

// ---------------- layernorm kernels ----------------
__global__ __launch_bounds__(256)
void ln1_kernel(const float* __restrict__ x, const float* __restrict__ w,
                float* __restrict__ h0f, u16* __restrict__ h0b)
{
  int row = blockIdx.x, tid = threadIdx.x;
  const float4* xr = (const float4*)(x + (size_t)row*1024);
  float4 v = xr[tid];
  float s1 = v.x+v.y+v.z+v.w;
  float s2 = v.x*v.x+v.y*v.y+v.z*v.z+v.w*v.w;
  #pragma unroll
  for (int m=1;m<64;m<<=1){ s1 += __shfl_xor(s1,m); s2 += __shfl_xor(s2,m); }
  __shared__ float red[8];
  int wv = tid>>6;
  if ((tid&63)==0){ red[wv]=s1; red[4+wv]=s2; }
  __syncthreads();
  s1 = red[0]+red[1]+red[2]+red[3];
  s2 = red[4]+red[5]+red[6]+red[7];
  float mu  = s1*(1.f/1024.f);
  float var = s2*(1.f/1024.f) - mu*mu;
  float rstd = rsqrtf(var + 1e-5f);
  float4 wv4 = ((const float4*)w)[tid];
  float o0 = softplusf((v.x-mu)*rstd*wv4.x);
  float o1 = softplusf((v.y-mu)*rstd*wv4.y);
  float o2 = softplusf((v.z-mu)*rstd*wv4.z);
  float o3 = softplusf((v.w-mu)*rstd*wv4.w);
  ((float4*)(h0f + (size_t)row*1024))[tid] = make_float4(o0,o1,o2,o3);
  u16x4 ob = { f2b(o0), f2b(o1), f2b(o2), f2b(o3) };
  *(u16x4*)(h0b + (size_t)row*1024 + tid*4) = ob;
}

__global__ __launch_bounds__(256)
void ln2_kernel(const float* __restrict__ x, const float* __restrict__ w,
                u16* __restrict__ outb)
{
  int row = blockIdx.x, tid = threadIdx.x;
  const float4* xr = (const float4*)(x + (size_t)row*1024);
  float4 v = xr[tid];
  float s1 = v.x+v.y+v.z+v.w;
  float s2 = v.x*v.x+v.y*v.y+v.z*v.z+v.w*v.w;
  #pragma unroll
  for (int m=1;m<64;m<<=1){ s1 += __shfl_xor(s1,m); s2 += __shfl_xor(s2,m); }
  __shared__ float red[8];
  int wv = tid>>6;
  if ((tid&63)==0){ red[wv]=s1; red[4+wv]=s2; }
  __syncthreads();
  s1 = red[0]+red[1]+red[2]+red[3];
  s2 = red[4]+red[5]+red[6]+red[7];
  float mu  = s1*(1.f/1024.f);
  float var = s2*(1.f/1024.f) - mu*mu;
  float rstd = rsqrtf(var + 1e-5f);
  float4 wv4 = ((const float4*)w)[tid];
  u16x4 ob = { f2b((v.x-mu)*rstd*wv4.x), f2b((v.y-mu)*rstd*wv4.y),
               f2b((v.z-mu)*rstd*wv4.z), f2b((v.w-mu)*rstd*wv4.w) };
  *(u16x4*)(outb + (size_t)row*1024 + tid*4) = ob;
}

// ---------------- MFMA GEMM: C[M,N] = A[M,K] (bf16) @ B[N,K]^T (bf16) ----------------
// EPI 0: store bf16   1: softplus(acc+bias[col]) -> f32   2: gelu -> bf16   3: acc+resid -> f32
template<int EPI>
__global__ __launch_bounds__(256)
void gemm_bt(const u16* __restrict__ A, int lda,
             const u16* __restrict__ B, int ldb, int K,
             float* __restrict__ outF, u16* __restrict__ outB, int ldo,
             const float* __restrict__ bias, const float* __restrict__ resid)
{
  __shared__ u16 sA[128*32];
  __shared__ u16 sB[128*32];
  const int tid = threadIdx.x;
  const int m0 = blockIdx.y * 128, n0 = blockIdx.x * 128;
  const int wave = tid>>6, lane = tid&63;
  const int wm = (wave>>1)*64, wn = (wave&1)*64;
  const int lr = lane&15, quad = lane>>4;

  floatx4 acc[4][4];
  #pragma unroll
  for (int i=0;i<4;i++)
    #pragma unroll
    for (int j=0;j<4;j++){ floatx4 z = {0.f,0.f,0.f,0.f}; acc[i][j]=z; }

  const int r0 = tid>>2, ko0 = (tid&3)*8;
  for (int k0=0; k0<K; k0+=32){
    __syncthreads();
    async_copy16(A + (size_t)(m0+r0)*lda    + k0+ko0, &sA[(size_t)tid*8]);
    async_copy16(A + (size_t)(m0+64+r0)*lda + k0+ko0, &sA[(size_t)(tid+256)*8]);
    async_copy16(B + (size_t)(n0+r0)*ldb    + k0+ko0, &sB[(size_t)tid*8]);
    async_copy16(B + (size_t)(n0+64+r0)*ldb + k0+ko0, &sB[(size_t)(tid+256)*8]);
    __syncthreads();
    short8 af[4], bf[4];
    #pragma unroll
    for (int i=0;i<4;i++){
      af[i] = *(const short8*)&sA[(wm+i*16+lr)*32 + quad*8];
      bf[i] = *(const short8*)&sB[(wn+i*16+lr)*32 + quad*8];
    }
    #pragma unroll
    for (int i=0;i<4;i++)
      #pragma unroll
      for (int j=0;j<4;j++)
        acc[i][j] = __builtin_amdgcn_mfma_f32_16x16x32_bf16(af[i], bf[j], acc[i][j], 0,0,0);
  }
  #pragma unroll
  for (int i=0;i<4;i++){
    #pragma unroll
    for (int j=0;j<4;j++){
      #pragma unroll
      for (int r=0;r<4;r++){
        int gr = m0 + wm + i*16 + quad*4 + r;   // C/D: row = quad*4+reg
        int gc = n0 + wn + j*16 + lr;           // C/D: col = lane&15
        float v = acc[i][j][r];
        size_t o = (size_t)gr*ldo + gc;
        if (EPI==0)      outB[o] = f2b(v);
        else if (EPI==1) outF[o] = softplusf(v + bias[gc]);
        else if (EPI==2) outB[o] = f2b(geluf(v));
        else             outF[o] = v + resid[o];
      }
    }
  }
}

// ---------------- chunked selective scan ----------------
// chains: (b, d) = 4096; L=1024 split into 64 chunks of 16. Lane owns (b, d, chunk),
// holds 16 n-states in registers. B/C are wave-uniform -> scalar loads from BCf.
// blk bits: [0:2)=d-block(4), [2:8)=chunk(64), [8:10)=b(4) -> grid 1024
__global__ __launch_bounds__(256)
void scan_p1(const float* __restrict__ delta, const float* __restrict__ h0f,
             const float* __restrict__ BCf, const float* __restrict__ A_log,
             float* __restrict__ Pbuf, float* __restrict__ Sbuf)
{
  int blk = blockIdx.x;
  int d = (blk & 3)*256 + threadIdx.x;
  int c = (blk >> 2) & 63;
  int b = blk >> 8;
  float a2[16], h[16], P[16];
  #pragma unroll
  for (int n=0;n<16;n++){ a2[n] = -__expf(A_log[d*16+n]) * 1.44269504f; h[n]=0.f; P[n]=1.f; }
  int t0 = c*16;
  const float* dptr = delta + ((size_t)(b*1024 + t0))*1024 + d;
  const float* xptr = h0f   + ((size_t)(b*1024 + t0))*1024 + d;
  const float* bc   = BCf   + ((size_t)(b*1024 + t0))*32;
  #pragma unroll 4
  for (int t=0;t<16;t++){
    float dlt = dptr[t*1024];
    float xv  = xptr[t*1024];
    float dx = dlt*xv;
    #pragma unroll
    for (int n=0;n<16;n++){
      float dA = exp2f(dlt*a2[n]);
      h[n] = dA*h[n] + dx*bc[t*32+n];
      P[n] *= dA;
    }
  }
  size_t base = ((size_t)((b*64 + c)*16))*1024 + d;
  #pragma unroll
  for (int n=0;n<16;n++){ Pbuf[base + (size_t)n*1024] = P[n]; Sbuf[base + (size_t)n*1024] = h[n]; }
}

// blk bits: [0:2)=d-block(4), [2:6)=n(16), [6:8)=b(4) -> grid 256
__global__ __launch_bounds__(256)
void scan_p2(const float* __restrict__ Pbuf, const float* __restrict__ Sbuf,
             float* __restrict__ Hbuf)
{
  int blk = blockIdx.x;
  int d = (blk & 3)*256 + threadIdx.x;
  int n = (blk >> 2) & 15;
  int b = blk >> 6;
  float H = 0.f;
  for (int c=0;c<64;c++){
    size_t idx = ((size_t)((b*64 + c)*16 + n))*1024 + d;
    Hbuf[idx] = H;
    H = Pbuf[idx]*H + Sbuf[idx];
  }
}

__global__ __launch_bounds__(256)
void scan_p3(const float* __restrict__ delta, const float* __restrict__ h0f,
             const float* __restrict__ BCf, const float* __restrict__ A_log,
             const float* __restrict__ Hbuf, const float* __restrict__ Dp,
             float* __restrict__ h1f)
{
  int blk = blockIdx.x;
  int d = (blk & 3)*256 + threadIdx.x;
  int c = (blk >> 2) & 63;
  int b = blk >> 8;
  float a2[16], h[16];
  size_t hb = ((size_t)((b*64 + c)*16))*1024 + d;
  #pragma unroll
  for (int n=0;n<16;n++){
    a2[n] = -__expf(A_log[d*16+n]) * 1.44269504f;
    h[n] = Hbuf[hb + (size_t)n*1024];
  }
  float dpv = 1.f + Dp[d];
  int t0 = c*16;
  const float* dptr = delta + ((size_t)(b*1024 + t0))*1024 + d;
  const float* xptr = h0f   + ((size_t)(b*1024 + t0))*1024 + d;
  const float* bc   = BCf   + ((size_t)(b*1024 + t0))*32;
  float* optr = h1f + ((size_t)(b*1024 + t0))*1024 + d;
  #pragma unroll 4
  for (int t=0;t<16;t++){
    float dlt = dptr[t*1024];
    float xv  = xptr[t*1024];
    float dx = dlt*xv;
    float y = 0.f;
    #pragma unroll
    for (int n=0;n<16;n++){
      float dA = exp2f(dlt*a2[n]);
      h[n] = dA*h[n] + dx*bc[t*32+n];
      y += h[n]*bc[t*32+16+n];
    }
    optr[t*1024] = xv*dpv + y;
  }
}

// ---------------- launch ----------------
extern "C" void kernel_launch(void* const* d_in, const int* in_sizes, int n_in,
                              void* d_out, int out_size, void* d_ws, size_t ws_size,
                              hipStream_t stream)
{
  const float* x    = (const float*)d_in[0];
  const float* ln1w = (const float*)d_in[1];
  const float* ln2w = (const float*)d_in[2];
  const float* Wdbc = (const float*)d_in[3];
  const float* Wdt  = (const float*)d_in[4];
  const float* bdt  = (const float*)d_in[5];
  const float* Alog = (const float*)d_in[6];
  const float* Dp   = (const float*)d_in[7];
  const float* Wfc  = (const float*)d_in[8];
  const float* Wproj= (const float*)d_in[9];
  float* out = (float*)d_out;

  char* ws = (char*)d_ws;
  size_t off = 0;
  auto carve = [&](size_t bytes)->char*{ char* p = ws + off; off += (bytes + 255) & ~(size_t)255; return p; };
  const size_t T = 4096;                       // B*L tokens
  float* h0f   = (float*)carve(T*1024*4);
  float* h1f   = (float*)carve(T*1024*4);
  float* dlt   = (float*)carve(T*1024*4);
  float* Pbuf  = (float*)carve((size_t)4*64*16*1024*4);
  float* Sbuf  = (float*)carve((size_t)4*64*16*1024*4);
  float* Hbuf  = (float*)carve((size_t)4*64*16*1024*4);
  float* BCf   = (float*)carve(T*32*4);
  u16*   h0b   = (u16*)  carve(T*1024*2);
  u16*   m0b   = (u16*)  carve(T*1024*2);
  u16*   g_b   = (u16*)  carve(T*4096*2);
  u16*   dbc_b = (u16*)  carve(T*128*2);
  u16*   Wdbc_b= (u16*)  carve((size_t)128*1024*2);
  u16*   Wdt_b = (u16*)  carve((size_t)1024*64*2);
  u16*   Wfc_b = (u16*)  carve((size_t)4096*1024*2);
  u16*   Wpj_b = (u16*)  carve((size_t)1024*4096*2);
  (void)ws_size; (void)in_sizes; (void)n_in; (void)out_size;

  // weight casts
  cast_dbc_pad<<<512, 256, 0, stream>>>(Wdbc, Wdbc_b);
  cast_kernel <<<256, 256, 0, stream>>>(Wdt, Wdt_b, 1024*64);
  cast_kernel <<<16384,256, 0, stream>>>(Wfc, Wfc_b, 4096*1024);
  cast_kernel <<<16384,256, 0, stream>>>(Wproj, Wpj_b, 1024*4096);

  // h0 = softplus(LN1(x))
  ln1_kernel<<<4096, 256, 0, stream>>>(x, ln1w, h0f, h0b);

  // dbc = h0 @ W_dbc^T  (N padded to 128), bf16 out
  gemm_bt<0><<<dim3(1,32), 256, 0, stream>>>(h0b, 1024, Wdbc_b, 1024, 1024,
                                             nullptr, dbc_b, 128, nullptr, nullptr);
  bc_conv<<<512, 256, 0, stream>>>(dbc_b, BCf);

  // delta = softplus(dbc[:, :64] @ W_dt^T + b_dt), f32 out
  gemm_bt<1><<<dim3(8,32), 256, 0, stream>>>(dbc_b, 128, Wdt_b, 64, 64,
                                             dlt, nullptr, 1024, bdt, nullptr);

  // selective scan -> h1 = h0*(1+Dp) + y
  scan_p1<<<1024, 256, 0, stream>>>(dlt, h0f, BCf, Alog, Pbuf, Sbuf);
  scan_p2<<<256,  256, 0, stream>>>(Pbuf, Sbuf, Hbuf);
  scan_p3<<<1024, 256, 0, stream>>>(dlt, h0f, BCf, Alog, Hbuf, Dp, h1f);

  // m0 = LN2(h1) (bf16)
  ln2_kernel<<<4096, 256, 0, stream>>>(h1f, ln2w, m0b);

  // g = gelu(m0 @ W_fc^T) (bf16)
  gemm_bt<2><<<dim3(32,32), 256, 0, stream>>>(m0b, 1024, Wfc_b, 1024, 1024,
                                              nullptr, g_b, 4096, nullptr, nullptr);

  // out = h1 + g @ W_proj^T (f32)
  gemm_bt<3><<<dim3(8,32), 256, 0, stream>>>(g_b, 4096, Wpj_b, 4096, 4096,
                                             out, nullptr, 1024, nullptr, h1f);
}

// Round 2
// 364.659 us; speedup vs baseline: 1.0970x; 1.0970x over previous
//
#include <hip/hip_runtime.h>
#include <cstdint>
#include <cstddef>

typedef unsigned short u16;
typedef unsigned int u32;
typedef __attribute__((ext_vector_type(8))) short short8;
typedef __attribute__((ext_vector_type(4))) float floatx4;
typedef __attribute__((ext_vector_type(4))) u16 u16x4;

#define DEV static __device__ __forceinline__

DEV u16 f2b(float f){ u32 u = __float_as_uint(f); u32 r = u + 0x7fffu + ((u>>16)&1u); return (u16)(r>>16); }
DEV float softplusf(float z){ return fmaxf(z,0.f) + log1pf(__expf(-fabsf(z))); }
DEV float fast_tanhf(float u){ float e = __expf(2.f*u); return 1.f - 2.f/(e+1.f); }
DEV float geluf(float x){ float u = 0.7978845608028654f*(x + 0.044715f*x*x*x); return 0.5f*x*(1.f+fast_tanhf(u)); }

DEV void async_copy16(const void* gp, void* lp){
  __builtin_amdgcn_global_load_lds((const __attribute__((address_space(1))) u32*)gp,
                                   (__attribute__((address_space(3))) u32*)lp, 16, 0, 0);
}

// ---------------- cast kernels ----------------
__global__ void cast_kernel(const float* __restrict__ src, u16* __restrict__ dst, int n){
  int i = blockIdx.x*256 + threadIdx.x;
  if (i < n) dst[i] = f2b(src[i]);
}

__global__ void cast4_kernel(const float* __restrict__ src, u16* __restrict__ dst, int n4){
  int i = blockIdx.x*256 + threadIdx.x;
  if (i < n4){
    float4 v = ((const float4*)src)[i];
    u16x4 o = { f2b(v.x), f2b(v.y), f2b(v.z), f2b(v.w) };
    *(u16x4*)(dst + i*4) = o;
  }
}

// W_dbc is (96,1024); pad to (128,1024) with zeros so the 128-wide N tile is valid.
__global__ void cast_dbc_pad(const float* __restrict__ src, u16* __restrict__ dst){
  int i = blockIdx.x*256 + threadIdx.x;          // 131072 = 128*1024
  int r = i >> 10;
  dst[i] = (r < 96) ? f2b(src[i]) : (u16)0;
}

// reduce 8 dbc split-K partials -> delta-GEMM bf16 input (cols 0..63) + f32 B/C buffer (cols 64..95)
__global__ void dbc_post(const float* __restrict__ p, u16* __restrict__ delta_in,
                         float* __restrict__ BCf){
  int e = blockIdx.x*256 + threadIdx.x;          // 524288 = 4096*128
  int t = e >> 7, c = e & 127;
  float s = 0.f;
  #pragma unroll
  for (int z=0;z<8;z++) s += p[(size_t)z*524288 + e];
  if (c < 64)      delta_in[t*64 + c] = f2b(s);
  else if (c < 96) BCf[t*32 + (c-64)] = s;
}

// out = p0 + p1 + h1  (proj split-K reduce + residual), float4-vectorized over 4M elems
__global__ void proj_reduce(const float* __restrict__ p, const float* __restrict__ h1f,
                            float* __restrict__ out){
  int i = blockIdx.x*256 + threadIdx.x;          // over 1M float4
  float4 a = ((const float4*)p)[i];
  float4 b = ((const float4*)(p + (size_t)4194304))[i];
  float4 r = ((const float4*)h1f)[i];
  float4 o = make_float4(a.x+b.x+r.x, a.y+b.y+r.y, a.z+b.z+r.z, a.w+b.w+r.w);
  ((float4*)out)[i] = o;
}

// ---------------- layernorm kernels ----------------
__global__ __launch_bounds__(256)
void ln1_kernel(const float* __restrict__ x, const float* __restrict__ w,
                float* __restrict__ h0f, u16* __restrict__ h0b)
{
  int row = blockIdx.x, tid = threadIdx.x;
  const float4* xr = (const float4*)(x + (size_t)row*1024);
  float4 v = xr[tid];
  float s1 = v.x+v.y+v.z+v.w;
  float s2 = v.x*v.x+v.y*v.y+v.z*v.z+v.w*v.w;
  #pragma unroll
  for (int m=1;m<64;m<<=1){ s1 += __shfl_xor(s1,m); s2 += __shfl_xor(s2,m); }
  __shared__ float red[8];
  int wv = tid>>6;
  if ((tid&63)==0){ red[wv]=s1; red[4+wv]=s2; }
  __syncthreads();
  s1 = red[0]+red[1]+red[2]+red[3];
  s2 = red[4]+red[5]+red[6]+red[7];
  float mu  = s1*(1.f/1024.f);
  float var = s2*(1.f/1024.f) - mu*mu;
  float rstd = rsqrtf(var + 1e-5f);
  float4 wv4 = ((const float4*)w)[tid];
  float o0 = softplusf((v.x-mu)*rstd*wv4.x);
  float o1 = softplusf((v.y-mu)*rstd*wv4.y);
  float o2 = softplusf((v.z-mu)*rstd*wv4.z);
  float o3 = softplusf((v.w-mu)*rstd*wv4.w);
  ((float4*)(h0f + (size_t)row*1024))[tid] = make_float4(o0,o1,o2,o3);
  u16x4 ob = { f2b(o0), f2b(o1), f2b(o2), f2b(o3) };
  *(u16x4*)(h0b + (size_t)row*1024 + tid*4) = ob;
}

__global__ __launch_bounds__(256)
void ln2_kernel(const float* __restrict__ x, const float* __restrict__ w,
                u16* __restrict__ outb)
{
  int row = blockIdx.x, tid = threadIdx.x;
  const float4* xr = (const float4*)(x + (size_t)row*1024);
  float4 v = xr[tid];
  float s1 = v.x+v.y+v.z+v.w;
  float s2 = v.x*v.x+v.y*v.y+v.z*v.z+v.w*v.w;
  #pragma unroll
  for (int m=1;m<64;m<<=1){ s1 += __shfl_xor(s1,m); s2 += __shfl_xor(s2,m); }
  __shared__ float red[8];
  int wv = tid>>6;
  if ((tid&63)==0){ red[wv]=s1; red[4+wv]=s2; }
  __syncthreads();
  s1 = red[0]+red[1]+red[2]+red[3];
  s2 = red[4]+red[5]+red[6]+red[7];
  float mu  = s1*(1.f/1024.f);
  float var = s2*(1.f/1024.f) - mu*mu;
  float rstd = rsqrtf(var + 1e-5f);
  float4 wv4 = ((const float4*)w)[tid];
  u16x4 ob = { f2b((v.x-mu)*rstd*wv4.x), f2b((v.y-mu)*rstd*wv4.y),
               f2b((v.z-mu)*rstd*wv4.z), f2b((v.w-mu)*rstd*wv4.w) };
  *(u16x4*)(outb + (size_t)row*1024 + tid*4) = ob;
}

// ---------------- MFMA GEMM: C[M,N] = A[M,K'] (bf16) @ B[N,K']^T (bf16) ----------------
// K = per-z-slice depth; k-range = [blockIdx.z*K, (blockIdx.z+1)*K).
// LDS layout is XOR-swizzled on the K-slot: LDS slot s of row r holds global k-chunk
// s ^ ((r>>1)&3). global_load_lds forces dest = base + lane*16, so the swizzle is applied
// on the SOURCE address (coalescing-neutral: same 64B span, permuted within).
// Reads then spread across all 8 bank-quads -> 2-way aliasing only (free, m136).
// EPI 1: softplus(acc+bias[col]) -> f32   2: gelu -> bf16   4: f32 partial at z*zstr
template<int EPI>
__global__ __launch_bounds__(256)
void gemm_bt(const u16* __restrict__ A, int lda,
             const u16* __restrict__ B, int ldb, int K,
             float* __restrict__ outF, u16* __restrict__ outB, int ldo,
             const float* __restrict__ bias, size_t zstr)
{
  __shared__ u16 sA[128*32];
  __shared__ u16 sB[128*32];
  const int tid = threadIdx.x;
  const int m0 = blockIdx.y * 128, n0 = blockIdx.x * 128;
  const int kstart = blockIdx.z * K;
  const int wave = tid>>6, lane = tid&63;
  const int wm = (wave>>1)*64, wn = (wave&1)*64;
  const int lr = lane&15, quad = lane>>4;

  floatx4 acc[4][4];
  #pragma unroll
  for (int i=0;i<4;i++)
    #pragma unroll
    for (int j=0;j<4;j++){ floatx4 z = {0.f,0.f,0.f,0.f}; acc[i][j]=z; }

  const int r0 = tid>>2;
  const int kc8 = (((tid&3) ^ ((tid>>3)&3)))*8;   // swizzled source k-offset (u16 units)
  const int sswz = ((lr>>1)&3);                    // reader slot xor term
  for (int k0=kstart; k0<kstart+K; k0+=32){
    __syncthreads();
    async_copy16(A + (size_t)(m0+r0)*lda    + k0+kc8, &sA[(size_t)tid*8]);
    async_copy16(A + (size_t)(m0+64+r0)*lda + k0+kc8, &sA[(size_t)(tid+256)*8]);
    async_copy16(B + (size_t)(n0+r0)*ldb    + k0+kc8, &sB[(size_t)tid*8]);
    async_copy16(B + (size_t)(n0+64+r0)*ldb + k0+kc8, &sB[(size_t)(tid+256)*8]);
    __syncthreads();
    short8 af[4], bf[4];
    #pragma unroll
    for (int i=0;i<4;i++){
      af[i] = *(const short8*)&sA[(wm+i*16+lr)*32 + (quad^sswz)*8];
      bf[i] = *(const short8*)&sB[(wn+i*16+lr)*32 + (quad^sswz)*8];
    }
    #pragma unroll
    for (int i=0;i<4;i++)
      #pragma unroll
      for (int j=0;j<4;j++)
        acc[i][j] = __builtin_amdgcn_mfma_f32_16x16x32_bf16(af[i], bf[j], acc[i][j], 0,0,0);
  }
  #pragma unroll
  for (int i=0;i<4;i++){
    #pragma unroll
    for (int j=0;j<4;j++){
      #pragma unroll
      for (int r=0;r<4;r++){
        int gr = m0 + wm + i*16 + quad*4 + r;   // C/D: row = quad*4+reg
        int gc = n0 + wn + j*16 + lr;           // C/D: col = lane&15
        float v = acc[i][j][r];
        size_t o = (size_t)gr*ldo + gc;
        if (EPI==1)      outF[o] = softplusf(v + bias[gc]);
        else if (EPI==2) outB[o] = f2b(geluf(v));
        else             outF[zstr*blockIdx.z + o] = v;    // EPI==4 split-K partial
      }
    }
  }
}

// ---------------- chunked selective scan ----------------
// chains: (b, d) = 4096; L=1024 split into 64 chunks of 16. Lane owns (b, d, chunk),
// holds 16 n-states in registers. B/C are wave-uniform -> scalar loads from BCf.
// blk bits: [0:2)=d-block(4), [2:8)=chunk(64), [8:10)=b(4) -> grid 1024
__global__ __launch_bounds__(256)
void scan_p1(const float* __restrict__ delta, const float* __restrict__ h0f,
             const float* __restrict__ BCf, const float* __restrict__ A_log,
             float* __restrict__ Pbuf, float* __restrict__ Sbuf)
{
  int blk = blockIdx.x;
  int d = (blk & 3)*256 + threadIdx.x;
  int c = (blk >> 2) & 63;
  int b = blk >> 8;
  float a2[16], h[16], P[16];
  #pragma unroll
  for (int n=0;n<16;n++){ a2[n] = -__expf(A_log[d*16+n]) * 1.44269504f; h[n]=0.f; P[n]=1.f; }
  int t0 = c*16;
  const float* dptr = delta + ((size_t)(b*1024 + t0))*1024 + d;
  const float* xptr = h0f   + ((size_t)(b*1024 + t0))*1024 + d;
  const float* bc   = BCf   + ((size_t)(b*1024 + t0))*32;
  #pragma unroll 4
  for (int t=0;t<16;t++){
    float dlt = dptr[t*1024];
    float xv  = xptr[t*1024];
    float dx = dlt*xv;
    #pragma unroll
    for (int n=0;n<16;n++){
      float dA = exp2f(dlt*a2[n]);
      h[n] = dA*h[n] + dx*bc[t*32+n];
      P[n] *= dA;
    }
  }
  size_t base = ((size_t)((b*64 + c)*16))*1024 + d;
  #pragma unroll
  for (int n=0;n<16;n++){ Pbuf[base + (size_t)n*1024] = P[n]; Sbuf[base + (size_t)n*1024] = h[n]; }
}

// blk bits: [0:2)=d-block(4), [2:6)=n(16), [6:8)=b(4) -> grid 256
__global__ __launch_bounds__(256)
void scan_p2(const float* __restrict__ Pbuf, const float* __restrict__ Sbuf,
             float* __restrict__ Hbuf)
{
  int blk = blockIdx.x;
  int d = (blk & 3)*256 + threadIdx.x;
  int n = (blk >> 2) & 15;
  int b = blk >> 6;
  float H = 0.f;
  for (int c=0;c<64;c++){
    size_t idx = ((size_t)((b*64 + c)*16 + n))*1024 + d;
    float P = Pbuf[idx], S = Sbuf[idx];
    Hbuf[idx] = H;
    H = P*H + S;
  }
}

__global__ __launch_bounds__(256)
void scan_p3(const float* __restrict__ delta, const float* __restrict__ h0f,
             const float* __restrict__ BCf, const float* __restrict__ A_log,
             const float* __restrict__ Hbuf, const float* __restrict__ Dp,
             float* __restrict__ h1f)
{
  int blk = blockIdx.x;
  int d = (blk & 3)*256 + threadIdx.x;
  int c = (blk >> 2) & 63;
  int b = blk >> 8;
  float a2[16], h[16];
  size_t hb = ((size_t)((b*64 + c)*16))*1024 + d;
  #pragma unroll
  for (int n=0;n<16;n++){
    a2[n] = -__expf(A_log[d*16+n]) * 1.44269504f;
    h[n] = Hbuf[hb + (size_t)n*1024];
  }
  float dpv = 1.f + Dp[d];
  int t0 = c*16;
  const float* dptr = delta + ((size_t)(b*1024 + t0))*1024 + d;
  const float* xptr = h0f   + ((size_t)(b*1024 + t0))*1024 + d;
  const float* bc   = BCf   + ((size_t)(b*1024 + t0))*32;
  float* optr = h1f + ((size_t)(b*1024 + t0))*1024 + d;
  #pragma unroll 4
  for (int t=0;t<16;t++){
    float dlt = dptr[t*1024];
    float xv  = xptr[t*1024];
    float dx = dlt*xv;
    float y = 0.f;
    #pragma unroll
    for (int n=0;n<16;n++){
      float dA = exp2f(dlt*a2[n]);
      h[n] = dA*h[n] + dx*bc[t*32+n];
      y += h[n]*bc[t*32+16+n];
    }
    optr[t*1024] = xv*dpv + y;
  }
}

// ---------------- launch ----------------
extern "C" void kernel_launch(void* const* d_in, const int* in_sizes, int n_in,
                              void* d_out, int out_size, void* d_ws, size_t ws_size,
                              hipStream_t stream)
{
  const float* x    = (const float*)d_in[0];
  const float* ln1w = (const float*)d_in[1];
  const float* ln2w = (const float*)d_in[2];
  const float* Wdbc = (const float*)d_in[3];
  const float* Wdt  = (const float*)d_in[4];
  const float* bdt  = (const float*)d_in[5];
  const float* Alog = (const float*)d_in[6];
  const float* Dp   = (const float*)d_in[7];
  const float* Wfc  = (const float*)d_in[8];
  const float* Wproj= (const float*)d_in[9];
  float* out = (float*)d_out;

  char* ws = (char*)d_ws;
  size_t off = 0;
  auto carve = [&](size_t bytes)->char*{ char* p = ws + off; off += (bytes + 255) & ~(size_t)255; return p; };
  const size_t T = 4096;                       // B*L tokens
  float* h0f   = (float*)carve(T*1024*4);
  float* h1f   = (float*)carve(T*1024*4);
  float* dlt   = (float*)carve(T*1024*4);
  float* Pbuf  = (float*)carve((size_t)4*64*16*1024*4);   // 16MB
  float* Sbuf  = (float*)carve((size_t)4*64*16*1024*4);   // 16MB, contiguous after Pbuf
  float* Hbuf  = (float*)carve((size_t)4*64*16*1024*4);   // 16MB
  float* BCf   = (float*)carve(T*32*4);
  u16*   h0b   = (u16*)  carve(T*1024*2);
  u16*   m0b   = (u16*)  carve(T*1024*2);
  u16*   g_b   = (u16*)  carve(T*4096*2);
  u16*   din_b = (u16*)  carve(T*64*2);
  u16*   Wdbc_b= (u16*)  carve((size_t)128*1024*2);
  u16*   Wdt_b = (u16*)  carve((size_t)1024*64*2);
  u16*   Wfc_b = (u16*)  carve((size_t)4096*1024*2);
  u16*   Wpj_b = (u16*)  carve((size_t)1024*4096*2);
  // lifetime-disjoint aliases (save 48MB):
  float* dbc_p  = Hbuf;   // 8 x 4096x128 f32 = 16MB; dead before scan_p2 writes Hbuf
  float* proj_p = Pbuf;   // 2 x 4096x1024 f32 = 32MB (spans Pbuf+Sbuf); P/S dead after scan_p2
  (void)ws_size; (void)in_sizes; (void)n_in; (void)out_size;

  // weight casts
  cast_dbc_pad<<<512, 256, 0, stream>>>(Wdbc, Wdbc_b);
  cast_kernel <<<256, 256, 0, stream>>>(Wdt, Wdt_b, 1024*64);
  cast4_kernel<<<4096,256, 0, stream>>>(Wfc, Wfc_b, 4096*1024/4);
  cast4_kernel<<<4096,256, 0, stream>>>(Wproj, Wpj_b, 1024*4096/4);

  // h0 = softplus(LN1(x))
  ln1_kernel<<<4096, 256, 0, stream>>>(x, ln1w, h0f, h0b);

  // dbc = h0 @ W_dbc^T  (N padded to 128), split-K=8 f32 partials
  gemm_bt<4><<<dim3(1,32,8), 256, 0, stream>>>(h0b, 1024, Wdbc_b, 1024, 128,
                                               dbc_p, nullptr, 128, nullptr, (size_t)T*128);
  // reduce partials -> delta-input bf16 + B/C f32
  dbc_post<<<2048, 256, 0, stream>>>(dbc_p, din_b, BCf);

  // delta = softplus(din @ W_dt^T + b_dt), f32 out
  gemm_bt<1><<<dim3(8,32), 256, 0, stream>>>(din_b, 64, Wdt_b, 64, 64,
                                             dlt, nullptr, 1024, bdt, 0);

  // selective scan -> h1 = h0*(1+Dp) + y
  scan_p1<<<1024, 256, 0, stream>>>(dlt, h0f, BCf, Alog, Pbuf, Sbuf);
  scan_p2<<<256,  256, 0, stream>>>(Pbuf, Sbuf, Hbuf);
  scan_p3<<<1024, 256, 0, stream>>>(dlt, h0f, BCf, Alog, Hbuf, Dp, h1f);

  // m0 = LN2(h1) (bf16)
  ln2_kernel<<<4096, 256, 0, stream>>>(h1f, ln2w, m0b);

  // g = gelu(m0 @ W_fc^T) (bf16)
  gemm_bt<2><<<dim3(32,32), 256, 0, stream>>>(m0b, 1024, Wfc_b, 1024, 1024,
                                              nullptr, g_b, 4096, nullptr, 0);

  // proj partials: g @ W_proj^T, split-K=2 (512 blocks -> 2 blocks/CU)
  gemm_bt<4><<<dim3(8,32,2), 256, 0, stream>>>(g_b, 4096, Wpj_b, 4096, 2048,
                                               proj_p, nullptr, 1024, nullptr, (size_t)T*1024);
  // out = p0 + p1 + h1
  proj_reduce<<<4096, 256, 0, stream>>>(proj_p, h1f, out);
}

// Round 3
// 356.744 us; speedup vs baseline: 1.1213x; 1.0222x over previous
//
#include <hip/hip_runtime.h>
#include <cstdint>
#include <cstddef>

typedef unsigned short u16;
typedef unsigned int u32;
typedef __attribute__((ext_vector_type(8))) short short8;
typedef __attribute__((ext_vector_type(4))) float floatx4;
typedef __attribute__((ext_vector_type(4))) u16 u16x4;

#define DEV static __device__ __forceinline__

DEV u16 f2b(float f){ u32 u = __float_as_uint(f); u32 r = u + 0x7fffu + ((u>>16)&1u); return (u16)(r>>16); }
DEV float softplusf(float z){ return fmaxf(z,0.f) + log1pf(__expf(-fabsf(z))); }
DEV float fast_tanhf(float u){ float e = __expf(2.f*u); return 1.f - 2.f/(e+1.f); }
DEV float geluf(float x){ float u = 0.7978845608028654f*(x + 0.044715f*x*x*x); return 0.5f*x*(1.f+fast_tanhf(u)); }

DEV void async_copy16(const void* gp, void* lp){
  __builtin_amdgcn_global_load_lds((const __attribute__((address_space(1))) u32*)gp,
                                   (__attribute__((address_space(3))) u32*)lp, 16, 0, 0);
}

// ---------------- fused weight prep: all four weight casts in one launch ----------------
// float4 segments: [0,32768)   Wdbc pad -> (128,1024) bf16 (rows>=96 zero)
//                  [32768,49152)   W_dt (1024,64)
//                  [49152,1097728) W_fc (4096,1024)
//                  [1097728,2146304) W_proj (1024,4096)
__global__ __launch_bounds__(256)
void prep_weights(const float* __restrict__ Wdbc, const float* __restrict__ Wdt,
                  const float* __restrict__ Wfc, const float* __restrict__ Wproj,
                  u16* __restrict__ dbc_b, u16* __restrict__ dt_b,
                  u16* __restrict__ fc_b, u16* __restrict__ pj_b)
{
  int i = blockIdx.x*256 + threadIdx.x;
  const float* src; u16* dst; int j;
  if (i < 32768){
    int e = i*4, r = e >> 10;
    if (r >= 96){ u16x4 z = {0,0,0,0}; *(u16x4*)(dbc_b + e) = z; return; }
    src = Wdbc; dst = dbc_b; j = i;
  } else if (i < 49152){ src = Wdt;   dst = dt_b; j = i - 32768; }
  else if (i < 1097728){ src = Wfc;   dst = fc_b; j = i - 49152; }
  else                 { src = Wproj; dst = pj_b; j = i - 1097728; }
  float4 v = ((const float4*)src)[j];
  u16x4 o = { f2b(v.x), f2b(v.y), f2b(v.z), f2b(v.w) };
  *(u16x4*)(dst + j*4) = o;
}

// reduce 8 dbc split-K partials -> delta-GEMM bf16 input (cols 0..63) + f32 B/C buffer (cols 64..95)
__global__ void dbc_post(const float* __restrict__ p, u16* __restrict__ delta_in,
                         float* __restrict__ BCf){
  int e = blockIdx.x*256 + threadIdx.x;          // 524288 = 4096*128
  int t = e >> 7, c = e & 127;
  float s = 0.f;
  #pragma unroll
  for (int z=0;z<8;z++) s += p[(size_t)z*524288 + e];
  if (c < 64)      delta_in[t*64 + c] = f2b(s);
  else if (c < 96) BCf[t*32 + (c-64)] = s;
}

// out = p0 + p1 + h1  (proj split-K reduce + residual), float4-vectorized over 4M elems
__global__ void proj_reduce(const float* __restrict__ p, const float* __restrict__ h1f,
                            float* __restrict__ out){
  int i = blockIdx.x*256 + threadIdx.x;          // over 1M float4
  float4 a = ((const float4*)p)[i];
  float4 b = ((const float4*)(p + (size_t)4194304))[i];
  float4 r = ((const float4*)h1f)[i];
  float4 o = make_float4(a.x+b.x+r.x, a.y+b.y+r.y, a.z+b.z+r.z, a.w+b.w+r.w);
  ((float4*)out)[i] = o;
}

// ---------------- layernorm kernels ----------------
__global__ __launch_bounds__(256)
void ln1_kernel(const float* __restrict__ x, const float* __restrict__ w,
                float* __restrict__ h0f, u16* __restrict__ h0b)
{
  int row = blockIdx.x, tid = threadIdx.x;
  const float4* xr = (const float4*)(x + (size_t)row*1024);
  float4 v = xr[tid];
  float s1 = v.x+v.y+v.z+v.w;
  float s2 = v.x*v.x+v.y*v.y+v.z*v.z+v.w*v.w;
  #pragma unroll
  for (int m=1;m<64;m<<=1){ s1 += __shfl_xor(s1,m); s2 += __shfl_xor(s2,m); }
  __shared__ float red[8];
  int wv = tid>>6;
  if ((tid&63)==0){ red[wv]=s1; red[4+wv]=s2; }
  __syncthreads();
  s1 = red[0]+red[1]+red[2]+red[3];
  s2 = red[4]+red[5]+red[6]+red[7];
  float mu  = s1*(1.f/1024.f);
  float var = s2*(1.f/1024.f) - mu*mu;
  float rstd = rsqrtf(var + 1e-5f);
  float4 wv4 = ((const float4*)w)[tid];
  float o0 = softplusf((v.x-mu)*rstd*wv4.x);
  float o1 = softplusf((v.y-mu)*rstd*wv4.y);
  float o2 = softplusf((v.z-mu)*rstd*wv4.z);
  float o3 = softplusf((v.w-mu)*rstd*wv4.w);
  ((float4*)(h0f + (size_t)row*1024))[tid] = make_float4(o0,o1,o2,o3);
  u16x4 ob = { f2b(o0), f2b(o1), f2b(o2), f2b(o3) };
  *(u16x4*)(h0b + (size_t)row*1024 + tid*4) = ob;
}

__global__ __launch_bounds__(256)
void ln2_kernel(const float* __restrict__ x, const float* __restrict__ w,
                u16* __restrict__ outb)
{
  int row = blockIdx.x, tid = threadIdx.x;
  const float4* xr = (const float4*)(x + (size_t)row*1024);
  float4 v = xr[tid];
  float s1 = v.x+v.y+v.z+v.w;
  float s2 = v.x*v.x+v.y*v.y+v.z*v.z+v.w*v.w;
  #pragma unroll
  for (int m=1;m<64;m<<=1){ s1 += __shfl_xor(s1,m); s2 += __shfl_xor(s2,m); }
  __shared__ float red[8];
  int wv = tid>>6;
  if ((tid&63)==0){ red[wv]=s1; red[4+wv]=s2; }
  __syncthreads();
  s1 = red[0]+red[1]+red[2]+red[3];
  s2 = red[4]+red[5]+red[6]+red[7];
  float mu  = s1*(1.f/1024.f);
  float var = s2*(1.f/1024.f) - mu*mu;
  float rstd = rsqrtf(var + 1e-5f);
  float4 wv4 = ((const float4*)w)[tid];
  u16x4 ob = { f2b((v.x-mu)*rstd*wv4.x), f2b((v.y-mu)*rstd*wv4.y),
               f2b((v.z-mu)*rstd*wv4.z), f2b((v.w-mu)*rstd*wv4.w) };
  *(u16x4*)(outb + (size_t)row*1024 + tid*4) = ob;
}

// ---------------- MFMA GEMM: C[M,N] = A[M,K'] (bf16) @ B[N,K']^T (bf16) ----------------
// LDS K-slot XOR-swizzled (round-2, bank-conflict-free).
// SWZ 0: 3D grid (n,m,z), K = z-slice depth.
// SWZ 1 (FC, 1D grid 1024): xcd=b&7 -> supertile (ms=xcd>>2 of 16 m-blks, ns=xcd&3 of
//        8 n-blks); per-XCD working set = 4MB A-stripe + 2MB B-stripe (k-window ~200KB).
// SWZ 2 (proj, 1D grid 512): xcd=b&7 -> (ms=xcd>>1 of 8 m-blks, z=xcd&1); n full 8.
// EPI 1: softplus(acc+bias[col]) -> f32   2: gelu -> bf16   4: f32 partial at z*zstr
template<int EPI, int SWZ>
__global__ __launch_bounds__(256)
void gemm_bt(const u16* __restrict__ A, int lda,
             const u16* __restrict__ B, int ldb, int K,
             float* __restrict__ outF, u16* __restrict__ outB, int ldo,
             const float* __restrict__ bias, size_t zstr)
{
  __shared__ u16 sA[128*32];
  __shared__ u16 sB[128*32];
  const int tid = threadIdx.x;
  int m_blk, n_blk, zb;
  if (SWZ == 0){ n_blk = blockIdx.x; m_blk = blockIdx.y; zb = blockIdx.z; }
  else if (SWZ == 1){
    int b = blockIdx.x, xcd = b & 7, local = b >> 3;
    m_blk = (xcd>>2)*16 + (local & 15);
    n_blk = (xcd&3)*8 + (local >> 4);
    zb = 0;
  } else {
    int b = blockIdx.x, xcd = b & 7, local = b >> 3;
    m_blk = (xcd>>1)*8 + (local & 7);
    n_blk = local >> 3;
    zb = xcd & 1;
  }
  const int m0 = m_blk*128, n0 = n_blk*128;
  const int kstart = zb * K;
  const int wave = tid>>6, lane = tid&63;
  const int wm = (wave>>1)*64, wn = (wave&1)*64;
  const int lr = lane&15, quad = lane>>4;

  floatx4 acc[4][4];
  #pragma unroll
  for (int i=0;i<4;i++)
    #pragma unroll
    for (int j=0;j<4;j++){ floatx4 z = {0.f,0.f,0.f,0.f}; acc[i][j]=z; }

  const int r0 = tid>>2;
  const int kc8 = (((tid&3) ^ ((tid>>3)&3)))*8;   // swizzled source k-offset (u16 units)
  const int sswz = ((lr>>1)&3);                    // reader slot xor term
  for (int k0=kstart; k0<kstart+K; k0+=32){
    __syncthreads();
    async_copy16(A + (size_t)(m0+r0)*lda    + k0+kc8, &sA[(size_t)tid*8]);
    async_copy16(A + (size_t)(m0+64+r0)*lda + k0+kc8, &sA[(size_t)(tid+256)*8]);
    async_copy16(B + (size_t)(n0+r0)*ldb    + k0+kc8, &sB[(size_t)tid*8]);
    async_copy16(B + (size_t)(n0+64+r0)*ldb + k0+kc8, &sB[(size_t)(tid+256)*8]);
    __syncthreads();
    short8 af[4], bf[4];
    #pragma unroll
    for (int i=0;i<4;i++){
      af[i] = *(const short8*)&sA[(wm+i*16+lr)*32 + (quad^sswz)*8];
      bf[i] = *(const short8*)&sB[(wn+i*16+lr)*32 + (quad^sswz)*8];
    }
    #pragma unroll
    for (int i=0;i<4;i++)
      #pragma unroll
      for (int j=0;j<4;j++)
        acc[i][j] = __builtin_amdgcn_mfma_f32_16x16x32_bf16(af[i], bf[j], acc[i][j], 0,0,0);
  }
  #pragma unroll
  for (int i=0;i<4;i++){
    #pragma unroll
    for (int j=0;j<4;j++){
      #pragma unroll
      for (int r=0;r<4;r++){
        int gr = m0 + wm + i*16 + quad*4 + r;   // C/D: row = quad*4+reg
        int gc = n0 + wn + j*16 + lr;           // C/D: col = lane&15
        float v = acc[i][j][r];
        size_t o = (size_t)gr*ldo + gc;
        if (EPI==1)      outF[o] = softplusf(v + bias[gc]);
        else if (EPI==2) outB[o] = f2b(geluf(v));
        else             outF[zstr*zb + o] = v;    // EPI==4 split-K partial
      }
    }
  }
}

// ---------------- chunked selective scan (32 chunks x 32 steps) ----------------
// chains: (b, d) = 4096. Lane owns (b, d, chunk), 16 n-states in registers.
// B/C are wave-uniform -> scalar loads from BCf.
// blk bits: [0:2)=d-block(4), [2:7)=chunk(32), [7:9)=b(4) -> grid 512
__global__ __launch_bounds__(256)
void scan_p1(const float* __restrict__ delta, const float* __restrict__ h0f,
             const float* __restrict__ BCf, const float* __restrict__ A_log,
             float* __restrict__ Pbuf, float* __restrict__ Sbuf)
{
  int blk = blockIdx.x;
  int d = (blk & 3)*256 + threadIdx.x;
  int c = (blk >> 2) & 31;
  int b = blk >> 7;
  float a2[16], h[16], P[16];
  #pragma unroll
  for (int n=0;n<16;n++){ a2[n] = -__expf(A_log[d*16+n]) * 1.44269504f; h[n]=0.f; P[n]=1.f; }
  int t0 = c*32;
  const float* dptr = delta + ((size_t)(b*1024 + t0))*1024 + d;
  const float* xptr = h0f   + ((size_t)(b*1024 + t0))*1024 + d;
  const float* bc   = BCf   + ((size_t)(b*1024 + t0))*32;
  #pragma unroll 4
  for (int t=0;t<32;t++){
    float dlt = dptr[t*1024];
    float xv  = xptr[t*1024];
    float dx = dlt*xv;
    #pragma unroll
    for (int n=0;n<16;n++){
      float dA = exp2f(dlt*a2[n]);
      h[n] = dA*h[n] + dx*bc[t*32+n];
      P[n] *= dA;
    }
  }
  size_t base = ((size_t)((b*32 + c)*16))*1024 + d;
  #pragma unroll
  for (int n=0;n<16;n++){ Pbuf[base + (size_t)n*1024] = P[n]; Sbuf[base + (size_t)n*1024] = h[n]; }
}

// blk bits: [0:2)=d-block(4), [2:6)=n(16), [6:8)=b(4) -> grid 256
__global__ __launch_bounds__(256)
void scan_p2(const float* __restrict__ Pbuf, const float* __restrict__ Sbuf,
             float* __restrict__ Hbuf)
{
  int blk = blockIdx.x;
  int d = (blk & 3)*256 + threadIdx.x;
  int n = (blk >> 2) & 15;
  int b = blk >> 6;
  float H = 0.f;
  for (int c=0;c<32;c++){
    size_t idx = ((size_t)((b*32 + c)*16 + n))*1024 + d;
    float P = Pbuf[idx], S = Sbuf[idx];
    Hbuf[idx] = H;
    H = P*H + S;
  }
}

__global__ __launch_bounds__(256)
void scan_p3(const float* __restrict__ delta, const float* __restrict__ h0f,
             const float* __restrict__ BCf, const float* __restrict__ A_log,
             const float* __restrict__ Hbuf, const float* __restrict__ Dp,
             float* __restrict__ h1f)
{
  int blk = blockIdx.x;
  int d = (blk & 3)*256 + threadIdx.x;
  int c = (blk >> 2) & 31;
  int b = blk >> 7;
  float a2[16], h[16];
  size_t hb = ((size_t)((b*32 + c)*16))*1024 + d;
  #pragma unroll
  for (int n=0;n<16;n++){
    a2[n] = -__expf(A_log[d*16+n]) * 1.44269504f;
    h[n] = Hbuf[hb + (size_t)n*1024];
  }
  float dpv = 1.f + Dp[d];
  int t0 = c*32;
  const float* dptr = delta + ((size_t)(b*1024 + t0))*1024 + d;
  const float* xptr = h0f   + ((size_t)(b*1024 + t0))*1024 + d;
  const float* bc   = BCf   + ((size_t)(b*1024 + t0))*32;
  float* optr = h1f + ((size_t)(b*1024 + t0))*1024 + d;
  #pragma unroll 4
  for (int t=0;t<32;t++){
    float dlt = dptr[t*1024];
    float xv  = xptr[t*1024];
    float dx = dlt*xv;
    float y = 0.f;
    #pragma unroll
    for (int n=0;n<16;n++){
      float dA = exp2f(dlt*a2[n]);
      h[n] = dA*h[n] + dx*bc[t*32+n];
      y += h[n]*bc[t*32+16+n];
    }
    optr[t*1024] = xv*dpv + y;
  }
}

// ---------------- launch ----------------
extern "C" void kernel_launch(void* const* d_in, const int* in_sizes, int n_in,
                              void* d_out, int out_size, void* d_ws, size_t ws_size,
                              hipStream_t stream)
{
  const float* x    = (const float*)d_in[0];
  const float* ln1w = (const float*)d_in[1];
  const float* ln2w = (const float*)d_in[2];
  const float* Wdbc = (const float*)d_in[3];
  const float* Wdt  = (const float*)d_in[4];
  const float* bdt  = (const float*)d_in[5];
  const float* Alog = (const float*)d_in[6];
  const float* Dp   = (const float*)d_in[7];
  const float* Wfc  = (const float*)d_in[8];
  const float* Wproj= (const float*)d_in[9];
  float* out = (float*)d_out;

  char* ws = (char*)d_ws;
  size_t off = 0;
  auto carve = [&](size_t bytes)->char*{ char* p = ws + off; off += (bytes + 255) & ~(size_t)255; return p; };
  const size_t T = 4096;                       // B*L tokens
  float* h0f   = (float*)carve(T*1024*4);
  float* h1f   = (float*)carve(T*1024*4);
  float* dlt   = (float*)carve(T*1024*4);
  float* Pbuf  = (float*)carve((size_t)4*32*16*1024*4);   // 8MB
  float* Sbuf  = (float*)carve((size_t)4*32*16*1024*4);   // 8MB
  float* Hbuf  = (float*)carve((size_t)4*32*16*1024*4);   // 8MB
  float* pad_  = (float*)carve((size_t)4*32*16*1024*4);   // 8MB (alias space)
  float* BCf   = (float*)carve(T*32*4);
  u16*   h0b   = (u16*)  carve(T*1024*2);
  u16*   m0b   = (u16*)  carve(T*1024*2);
  u16*   g_b   = (u16*)  carve(T*4096*2);
  u16*   din_b = (u16*)  carve(T*64*2);
  u16*   Wdbc_b= (u16*)  carve((size_t)128*1024*2);
  u16*   Wdt_b = (u16*)  carve((size_t)1024*64*2);
  u16*   Wfc_b = (u16*)  carve((size_t)4096*1024*2);
  u16*   Wpj_b = (u16*)  carve((size_t)1024*4096*2);
  // lifetime-disjoint aliases:
  float* dbc_p  = Hbuf;   // 8 x 4096x128 f32 = 16MB (Hbuf+pad_); dead before scan_p2 writes Hbuf
  float* proj_p = Pbuf;   // 2 x 4096x1024 f32 = 32MB (P+S+H+pad_); P/S/H dead after scan_p3
  (void)pad_; (void)ws_size; (void)in_sizes; (void)n_in; (void)out_size;

  // all weight casts in one launch
  prep_weights<<<8384, 256, 0, stream>>>(Wdbc, Wdt, Wfc, Wproj,
                                         Wdbc_b, Wdt_b, Wfc_b, Wpj_b);

  // h0 = softplus(LN1(x))
  ln1_kernel<<<4096, 256, 0, stream>>>(x, ln1w, h0f, h0b);

  // dbc = h0 @ W_dbc^T  (N padded to 128), split-K=8 f32 partials
  gemm_bt<4,0><<<dim3(1,32,8), 256, 0, stream>>>(h0b, 1024, Wdbc_b, 1024, 128,
                                                 dbc_p, nullptr, 128, nullptr, (size_t)T*128);
  // reduce partials -> delta-input bf16 + B/C f32
  dbc_post<<<2048, 256, 0, stream>>>(dbc_p, din_b, BCf);

  // delta = softplus(din @ W_dt^T + b_dt), f32 out
  gemm_bt<1,0><<<dim3(8,32), 256, 0, stream>>>(din_b, 64, Wdt_b, 64, 64,
                                               dlt, nullptr, 1024, bdt, 0);

  // selective scan -> h1 = h0*(1+Dp) + y
  scan_p1<<<512, 256, 0, stream>>>(dlt, h0f, BCf, Alog, Pbuf, Sbuf);
  scan_p2<<<256, 256, 0, stream>>>(Pbuf, Sbuf, Hbuf);
  scan_p3<<<512, 256, 0, stream>>>(dlt, h0f, BCf, Alog, Hbuf, Dp, h1f);

  // m0 = LN2(h1) (bf16)
  ln2_kernel<<<4096, 256, 0, stream>>>(h1f, ln2w, m0b);

  // g = gelu(m0 @ W_fc^T) (bf16) — XCD-supertiled 1D grid
  gemm_bt<2,1><<<1024, 256, 0, stream>>>(m0b, 1024, Wfc_b, 1024, 1024,
                                         nullptr, g_b, 4096, nullptr, 0);

  // proj partials: g @ W_proj^T, split-K=2 — XCD-supertiled 1D grid
  gemm_bt<4,2><<<512, 256, 0, stream>>>(g_b, 4096, Wpj_b, 4096, 2048,
                                        proj_p, nullptr, 1024, nullptr, (size_t)T*1024);
  // out = p0 + p1 + h1
  proj_reduce<<<4096, 256, 0, stream>>>(proj_p, h1f, out);
}